// Round 13
// baseline (201.185 us; speedup 1.0000x reference)
//
#include <hip/hip_runtime.h>
#include <hip/hip_bf16.h>
#include <math.h>

// B=2, N=4096, D=512, H=8, DH=64, SCALE=1/8 (folded into Wq pack)

typedef __attribute__((ext_vector_type(8))) short short8;
typedef __attribute__((ext_vector_type(4))) float floatx4;
typedef __attribute__((ext_vector_type(16))) float floatx16;
typedef __attribute__((ext_vector_type(4))) short shortx4;
typedef __attribute__((ext_vector_type(4))) int intx4;

__device__ __forceinline__ short f2bf(float f) {
  __hip_bfloat16 h = __float2bfloat16(f);
  return __builtin_bit_cast(short, h);
}

__device__ __forceinline__ float fexp2(float x) {
  float r;
  asm("v_exp_f32 %0, %1" : "=v"(r) : "v"(x));
  return r;
}

__device__ __forceinline__ int cvtpk(float lo, float hi) {
  int r;
  asm("v_cvt_pk_bf16_f32 %0, %1, %2" : "=v"(r) : "v"(lo), "v"(hi));
  return r;
}

__device__ __forceinline__ void gl_lds16(const void* g, void* l) {
  __builtin_amdgcn_global_load_lds(
      (__attribute__((address_space(1))) void*)(g),
      (__attribute__((address_space(3))) void*)(l), 16, 0, 0);
}

// hardened sync point: counted wait + instruction barrier, both compiler-fenced
// (race-free per rounds 8/11/12: absmax at the deterministic 1.2207e-4 floor)
#define SYNC_TILE(NSTR)                                        \
  asm volatile("s_waitcnt vmcnt(" NSTR ")" ::: "memory");      \
  __builtin_amdgcn_sched_barrier(0);                           \
  asm volatile("s_barrier" ::: "memory");                      \
  __builtin_amdgcn_sched_barrier(0);

// ---------------- combined pack kernel ----------------

__global__ __launch_bounds__(256) void pack_all(
    const float* __restrict__ x,
    const float* __restrict__ Wq, const float* __restrict__ Wk,
    const float* __restrict__ Wv, const float* __restrict__ Wo,
    const float* __restrict__ bo,
    const float* __restrict__ gq, const float* __restrict__ gk,
    const float* __restrict__ gv, const float* __restrict__ go,
    short* __restrict__ xb, short* __restrict__ Wcat,
    short* __restrict__ Wog, float* __restrict__ bog) {
  int b = blockIdx.x;
  int tid = threadIdx.x;
  if (b < 4096) {
    int i = b * 256 + tid;
    floatx4 v = *(const floatx4*)(x + (size_t)i * 4);
    shortx4 o;
    o[0] = f2bf(v[0]); o[1] = f2bf(v[1]); o[2] = f2bf(v[2]); o[3] = f2bf(v[3]);
    *(shortx4*)(xb + (size_t)i * 4) = o;
  } else {
    int i = (b - 4096) * 256 + tid;
    if (i < 786432) {                 // Wcat [1536,512]
      int j = i >> 9, kx = i & 511;
      int seg = j >> 9, jj = j & 511;
      float g, w;
      // fold SCALE=0.125 (exact pow2) ONLY — PROVEN numerics. The log2e fold
      // is 2-for-2 in accuracy failures (r6, r9); this path is 8-for-8
      // passing at the deterministic 1.2207e-4 floor. Do NOT fold log2e.
      if (seg == 0)      { g = gq[jj] * 0.125f; w = Wq[jj * 512 + kx]; }
      else if (seg == 1) { g = gk[jj];          w = Wk[jj * 512 + kx]; }
      else               { g = gv[jj];          w = Wv[jj * 512 + kx]; }
      Wcat[i] = f2bf(g * w);
    } else if (i < 786432 + 262144) { // Wog [512,512]
      int i2 = i - 786432;
      Wog[i2] = f2bf(go[i2 >> 9] * Wo[i2]);
    } else if (i < 786432 + 262144 + 512) {
      int i3 = i - 786432 - 262144;
      bog[i3] = go[i3] * bo[i3];
    }
  }
}

// ---------------- QKV projection GEMM (ring-3, counted vmcnt) -------------
// C[8192,1536] = xb @ Wcat^T; k stored [bh][n][64]; q AND v stored transposed
// [bh][64][n]. XCD swizzle (T1): 768 wgs, 96 contiguous per XCD.
// ROUND-13: (a) r12's Cs-transpose epilogue REVERTED (predicted -7-10us,
// delivered ~0: scatter stores were not the bottleneck; the transpose cost
// offset the coalescing gain). (b) The K-loop's single-buffered 2-barrier
// structure (stage -> syncthreads vmcnt(0)-drain -> compute -> syncthreads,
// 16 iters) replaced with the attn-proven ring-3 + counted-vmcnt + fenced
// single barrier: prefetch distance 2, vmcnt(4) = (2 tiles in flight x 4
// loads/wave) - own oldest tile; loads never drained in-loop. Cross-wave
// safety: each wave retires its OWN tile-t loads before the shared barrier
// -> after the barrier all producers' writes have landed (m201 mechanism,
// verified in attn r8/r11/r12). WAR: stage(t+2) at iter t overwrites slot
// (t+2)%3 = (t-1)%3, whose readers finished before the iter-t barrier.
// LDS 3 x (8KB A + 8KB B) = 48KB -> 3 WG/CU (matches grid's 3/CU exactly).

__global__ __launch_bounds__(256) void gemm_qkv(
    const short* __restrict__ A, const short* __restrict__ W,
    short* __restrict__ qt, short* __restrict__ k, short* __restrict__ vt) {
  __shared__ short As[3][4096];
  __shared__ short Bs[3][4096];
  const int tid = threadIdx.x;
  const int lane = tid & 63, wv = tid >> 6;
  const int wm = wv & 1, wn = wv >> 1;
  const int lrow = lane & 15, quad = lane >> 4;
  const int lin = blockIdx.y * 12 + blockIdx.x;   // 768 wgs total
  const int wg = (lin & 7) * 96 + (lin >> 3);     // bijective: 768 % 8 == 0
  const int m0 = (wg / 12) * 128, n0 = (wg % 12) * 128;
  const int srow = lane >> 2, skc = lane & 3;

  floatx4 acc[4][4];
  const floatx4 z4 = {0.f, 0.f, 0.f, 0.f};
#pragma unroll
  for (int a = 0; a < 4; a++)
#pragma unroll
    for (int b = 0; b < 4; b++) acc[a][b] = z4;

  // stage K-tile kidx into ring slot sl (4 gl_lds per wave)
  auto stage = [&](int kidx, int sl) {
    int kk = kidx * 32;
#pragma unroll
    for (int i = 0; i < 2; i++) {
      int rr = (wv * 2 + i) * 16 + srow;
      gl_lds16(A + (size_t)(m0 + rr) * 512 + kk + skc * 8, &As[sl][(wv * 2 + i) * 512]);
      gl_lds16(W + (size_t)(n0 + rr) * 512 + kk + skc * 8, &Bs[sl][(wv * 2 + i) * 512]);
    }
  };

  auto compute = [&](int sl) {
    const short* Ac = As[sl];
    const short* Bc = Bs[sl];
    short8 af[4], bfr[4];
#pragma unroll
    for (int t = 0; t < 4; t++) {
      af[t]  = *(const short8*)(Ac + (wm * 64 + t * 16 + lrow) * 32 + quad * 8);
      bfr[t] = *(const short8*)(Bc + (wn * 64 + t * 16 + lrow) * 32 + quad * 8);
    }
#pragma unroll
    for (int mt = 0; mt < 4; mt++)
#pragma unroll
      for (int nt = 0; nt < 4; nt++)
        acc[mt][nt] = __builtin_amdgcn_mfma_f32_16x16x32_bf16(af[mt], bfr[nt], acc[mt][nt], 0, 0, 0);
  };

  stage(0, 0); stage(1, 1);       // prologue: 2 tiles in flight
  for (int t = 0; t < 14; t++) {
    SYNC_TILE("4")                 // own tile-t loads retired; all waves aligned
    stage(t + 2, (t + 2) % 3);
    compute(t % 3);
  }
  SYNC_TILE("4")
  compute(2);                      // tile 14 -> slot 14%3=2
  SYNC_TILE("0")
  compute(0);                      // tile 15 -> slot 15%3=0

  // epilogue (r11-proven scatter form)
#pragma unroll
  for (int mt = 0; mt < 4; mt++)
#pragma unroll
    for (int nt = 0; nt < 4; nt++) {
      int gj = n0 + wn * 64 + nt * 16 + lrow;
      int seg = gj >> 9, hd = gj & 511;
      int hh = hd >> 6, dd = hd & 63;
      int gi0 = m0 + wm * 64 + mt * 16 + quad * 4;
      int bb = gi0 >> 12, nn = gi0 & 4095;
      if (seg == 1) {
        short* dst = k + ((size_t)(bb * 8 + hh) * 4096 + nn) * 64 + dd;
#pragma unroll
        for (int r = 0; r < 4; r++) dst[(size_t)r * 64] = f2bf(acc[mt][nt][r]);
      } else {
        shortx4 pk;
#pragma unroll
        for (int r = 0; r < 4; r++) pk[r] = f2bf(acc[mt][nt][r]);
        short* base = (seg == 0) ? qt : vt;
        *(shortx4*)(base + ((size_t)(bb * 8 + hh) * 64 + dd) * 4096 + nn) = pk;
      }
    }
}

// ---------------- flash attention (64q/wave, ring-4, counted vmcnt) -------
// UNCHANGED from r11/r12 (control): 95-96us, absmax = exact 1.2207e-4 floor.
// Numerics: scale-only pack, S zero-init, p = exp2(fma(S, log2e, -3*log2e)).
// Structure: ring-4 staging (128KB LDS, 1 WG/CU, prefetch distance 3,
// vmcnt(8)); hardened SYNC_TILE. WG = 512 thr = 4 pr (64q) x 2 hf (2048 kv);
// 256 WGs, XCD-swizzled (2 heads/XCD, K/V L2-resident). Halves combined
// in-LDS (stride-65 f32). Fragment layouts (32x32x16) verified r4-r12.

__global__ __launch_bounds__(512, 2) void attn(
    const short* __restrict__ Qt, const short* __restrict__ K,
    const short* __restrict__ Vt, short* __restrict__ R) {
  __shared__ short SMEM[65536];   // 128KB: K rings [0,32768), V rings [32768,65536)
  const int tid = threadIdx.x;
  const int lane = tid & 63, wv = tid >> 6;      // wv 0..7
  const int l31 = lane & 31, lh = lane >> 5;
  const int pr = wv >> 1, hf = wv & 1;           // pr: q-group 0..3, hf: kv-half
  const int lin = blockIdx.y * 16 + blockIdx.x;  // 256 wgs total
  const int wg = ((lin & 7) << 5) | (lin >> 3);  // bijective: 256 % 8 == 0
  const int bh = wg >> 4;
  const int q0 = (wg & 15) * 256 + pr * 64;

  const short* Qb = Qt + (size_t)bh * 64 * 4096;
  const short* Kb = K + (size_t)bh * 4096 * 64;
  const short* Vb = Vt + (size_t)bh * 64 * 4096;

  // Q fragments (B-operand), 2 q-tiles: qf[qt][ks][i] = Q[q0+qt*32+l31][ks*16+lh*8+i]
  short8 qf[2][4];
#pragma unroll
  for (int qt = 0; qt < 2; qt++)
#pragma unroll
    for (int ks = 0; ks < 4; ks++)
#pragma unroll
      for (int i = 0; i < 8; i++)
        qf[qt][ks][i] = Qb[(size_t)(ks * 16 + lh * 8 + i) * 4096 + q0 + qt * 32 + l31];
  asm volatile("s_waitcnt vmcnt(0)" ::: "memory");   // clean slate for counted vmcnt
  __builtin_amdgcn_sched_barrier(0);

  floatx16 O[2][2];
#pragma unroll
  for (int qt = 0; qt < 2; qt++)
#pragma unroll
    for (int dt = 0; dt < 2; dt++)
#pragma unroll
      for (int r = 0; r < 16; r++) O[qt][dt][r] = 0.f;
  float lsum[2] = {0.f, 0.f};

  // stage tile t of this wave's half into ring slot s (4 gl_lds per wave)
  auto stage = [&](int t, int s) {
    int n0 = (hf * 32 + t) * 64;
    short* Kd = SMEM + (hf * 4 + s) * 4096;
    short* Vd = SMEM + 32768 + (hf * 4 + s) * 4096;
#pragma unroll
    for (int i = 0; i < 2; i++) {
      int ci = i * 4 + pr;                        // 0..7 across the half's 4 waves
      gl_lds16(Kb + (size_t)(n0 + (ci >> 2) * 32 + l31) * 64 + (ci & 3) * 16 + lh * 8,
               Kd + ci * 512);
      gl_lds16(Vb + (size_t)((ci >> 2) * 32 + l31) * 4096 + n0 + ((ci >> 1) & 1) * 32 + (ci & 1) * 16 + lh * 8,
               Vd + ci * 512);
    }
  };

  auto compute = [&](int s) {
    const short* Kc = SMEM + (hf * 4 + s) * 4096;
    const short* Vc = SMEM + 32768 + (hf * 4 + s) * 4096;
    const float C0 = 1.44269504088896f;           // log2(e)
    const float C1 = -3.0f * 1.44269504088896f;   // fixed shift M=3
#pragma unroll
    for (int mt = 0; mt < 2; mt++) {
      short8 kf[4];
#pragma unroll
      for (int ks = 0; ks < 4; ks++)
        kf[ks] = *(const short8*)(Kc + ((mt * 4 + ks) * 64 + lane) * 8);

      short8 pf[2][2];
#pragma unroll
      for (int qt = 0; qt < 2; qt++) {
        floatx16 S;
#pragma unroll
        for (int r = 0; r < 16; r++) S[r] = 0.f;
#pragma unroll
        for (int ks = 0; ks < 4; ks++)
          S = __builtin_amdgcn_mfma_f32_32x32x16_bf16(kf[ks], qf[qt][ks], S, 0, 0, 0);

        // p = exp(s - 3): proven bf16-P quantization profile (p <= ~0.2)
        float p[16];
        float l0 = 0.f, l1 = 0.f, l2 = 0.f, l3 = 0.f;
#pragma unroll
        for (int r = 0; r < 16; r += 4) {
          p[r]     = fexp2(fmaf(S[r],     C0, C1)); l0 += p[r];
          p[r + 1] = fexp2(fmaf(S[r + 1], C0, C1)); l1 += p[r + 1];
          p[r + 2] = fexp2(fmaf(S[r + 2], C0, C1)); l2 += p[r + 2];
          p[r + 3] = fexp2(fmaf(S[r + 3], C0, C1)); l3 += p[r + 3];
        }
        lsum[qt] += (l0 + l1) + (l2 + l3);
#pragma unroll
        for (int kh = 0; kh < 2; kh++) {
          int A0 = cvtpk(p[8 * kh + 0], p[8 * kh + 1]);
          int B0 = cvtpk(p[8 * kh + 4], p[8 * kh + 5]);
          int A1 = cvtpk(p[8 * kh + 2], p[8 * kh + 3]);
          int B1 = cvtpk(p[8 * kh + 6], p[8 * kh + 7]);
          asm("v_permlane32_swap_b32 %0, %1" : "+v"(A0), "+v"(B0));
          asm("v_permlane32_swap_b32 %0, %1" : "+v"(A1), "+v"(B1));
          intx4 w4 = {A0, A1, B0, B1};
          pf[qt][kh] = __builtin_bit_cast(short8, w4);
        }
      }

#pragma unroll
      for (int kh = 0; kh < 2; kh++)
#pragma unroll
        for (int dt = 0; dt < 2; dt++) {
          short8 vf = *(const short8*)(Vc + (((dt * 2 + mt) * 2 + kh) * 64 + lane) * 8);
#pragma unroll
          for (int qt = 0; qt < 2; qt++)
            O[qt][dt] = __builtin_amdgcn_mfma_f32_32x32x16_bf16(vf, pf[qt][kh], O[qt][dt], 0, 0, 0);
        }
    }
  };

  // prologue: 3 tiles in flight (12 loads/wave)
  stage(0, 0); stage(1, 1); stage(2, 2);

  for (int t = 0; t < 29; t++) {
    SYNC_TILE("8")                 // own oldest tile retired; all waves aligned
    stage(t + 3, (t + 3) & 3);
    compute(t & 3);
  }
  // tail: tiles 29, 30, 31 (no more staging; drain progressively)
  SYNC_TILE("8")
  compute(1);
  SYNC_TILE("4")
  compute(2);
  SYNC_TILE("0")
  compute(3);

  // per-wave half-sum: add partner 32 lanes' rows
#pragma unroll
  for (int qt = 0; qt < 2; qt++) lsum[qt] += __shfl_xor(lsum[qt], 32, 64);

  // ---- combine the two kv-halves in-LDS (stride-65 f32: conflict-free) ----
  __syncthreads();                       // all ring reads done; safe to reuse
  float* Ob = (float*)SMEM;              // [ (pr*64+lane)*65 + e ], e = qt*32+dt*16+r
  float* Lb = Ob + 4 * 64 * 65;          // [ (pr*64+lane)*2 + qt ]
  if (hf == 1) {
    int base = (pr * 64 + lane) * 65;
#pragma unroll
    for (int qt = 0; qt < 2; qt++) {
#pragma unroll
      for (int dt = 0; dt < 2; dt++)
#pragma unroll
        for (int r = 0; r < 16; r++)
          Ob[base + qt * 32 + dt * 16 + r] = O[qt][dt][r];
      Lb[(pr * 64 + lane) * 2 + qt] = lsum[qt];
    }
  }
  __syncthreads();
  if (hf == 0) {
    int base = (pr * 64 + lane) * 65;
    const int b = bh >> 3, h = bh & 7;
#pragma unroll
    for (int qt = 0; qt < 2; qt++) {
      float tot = lsum[qt] + Lb[(pr * 64 + lane) * 2 + qt];
      float inv = 1.0f / tot;
      int row = q0 + qt * 32 + l31;
#pragma unroll
      for (int dt = 0; dt < 2; dt++)
#pragma unroll
        for (int g = 0; g < 4; g++) {
          shortx4 pk;
#pragma unroll
          for (int j = 0; j < 4; j++) {
            float v = O[qt][dt][g * 4 + j] + Ob[base + qt * 32 + dt * 16 + g * 4 + j];
            pk[j] = f2bf(v * inv);
          }
          int d0 = dt * 32 + g * 8 + lh * 4;
          *(shortx4*)(&R[((size_t)b * 4096 + row) * 512 + h * 64 + d0]) = pk;
        }
    }
  }
}

// ---------------- output projection GEMM (ring-3, counted vmcnt) ----------
// Same ring-3 conversion as gemm_qkv. Biggest relative win expected here:
// grid 256 = 1 WG/CU, so the old per-iter vmcnt(0) drain was FULLY exposed
// (no co-resident WG to hide it); prefetch distance 2 now covers it.

__global__ __launch_bounds__(256) void gemm_out(
    const short* __restrict__ A, const short* __restrict__ W,
    const float* __restrict__ bias, float* __restrict__ out) {
  __shared__ short As[3][4096];
  __shared__ short Bs[3][4096];
  const int tid = threadIdx.x;
  const int lane = tid & 63, wv = tid >> 6;
  const int wm = wv & 1, wn = wv >> 1;
  const int lrow = lane & 15, quad = lane >> 4;
  const int m0 = blockIdx.y * 128, n0 = blockIdx.x * 128;
  const int srow = lane >> 2, skc = lane & 3;

  floatx4 acc[4][4];
  const floatx4 z4 = {0.f, 0.f, 0.f, 0.f};
#pragma unroll
  for (int a = 0; a < 4; a++)
#pragma unroll
    for (int b = 0; b < 4; b++) acc[a][b] = z4;

  auto stage = [&](int kidx, int sl) {
    int kk = kidx * 32;
#pragma unroll
    for (int i = 0; i < 2; i++) {
      int rr = (wv * 2 + i) * 16 + srow;
      gl_lds16(A + (size_t)(m0 + rr) * 512 + kk + skc * 8, &As[sl][(wv * 2 + i) * 512]);
      gl_lds16(W + (size_t)(n0 + rr) * 512 + kk + skc * 8, &Bs[sl][(wv * 2 + i) * 512]);
    }
  };

  auto compute = [&](int sl) {
    const short* Ac = As[sl];
    const short* Bc = Bs[sl];
    short8 af[4], bfr[4];
#pragma unroll
    for (int t = 0; t < 4; t++) {
      af[t]  = *(const short8*)(Ac + (wm * 64 + t * 16 + lrow) * 32 + quad * 8);
      bfr[t] = *(const short8*)(Bc + (wn * 64 + t * 16 + lrow) * 32 + quad * 8);
    }
#pragma unroll
    for (int mt = 0; mt < 4; mt++)
#pragma unroll
      for (int nt = 0; nt < 4; nt++)
        acc[mt][nt] = __builtin_amdgcn_mfma_f32_16x16x32_bf16(af[mt], bfr[nt], acc[mt][nt], 0, 0, 0);
  };

  stage(0, 0); stage(1, 1);
  for (int t = 0; t < 14; t++) {
    SYNC_TILE("4")
    stage(t + 2, (t + 2) % 3);
    compute(t % 3);
  }
  SYNC_TILE("4")
  compute(2);
  SYNC_TILE("0")
  compute(0);

#pragma unroll
  for (int mt = 0; mt < 4; mt++)
#pragma unroll
    for (int nt = 0; nt < 4; nt++)
#pragma unroll
      for (int r = 0; r < 4; r++) {
        int gi = m0 + wm * 64 + mt * 16 + quad * 4 + r;
        int gj = n0 + wn * 64 + nt * 16 + lrow;
        out[(size_t)gi * 512 + gj] = acc[mt][nt][r] + bias[gj];
      }
}

// ---------------- launcher ----------------

extern "C" void kernel_launch(void* const* d_in, const int* in_sizes, int n_in,
                              void* d_out, int out_size, void* d_ws, size_t ws_size,
                              hipStream_t stream) {
  const float* x  = (const float*)d_in[0];
  const float* Wq = (const float*)d_in[1];
  const float* Wk = (const float*)d_in[2];
  const float* Wv = (const float*)d_in[3];
  const float* Wo = (const float*)d_in[4];
  const float* bo = (const float*)d_in[5];
  const float* gq = (const float*)d_in[6];
  const float* gk = (const float*)d_in[7];
  const float* gv = (const float*)d_in[8];
  const float* go = (const float*)d_in[9];

  char* ws = (char*)d_ws;
  short* xb   = (short*)(ws);               // 8 MB  [8192,512] bf16
  short* Wcat = (short*)(ws + 8388608);     // 1.5 MB [1536,512] bf16
  short* Wog  = (short*)(ws + 9961472);     // 0.5 MB [512,512] bf16
  float* bog  = (float*)(ws + 10485760);    // 2 KB
  short* qt   = (short*)(ws + 10487808);    // 8 MB [16][64][4096]
  short* kbuf = (short*)(ws + 18876416);    // 8 MB [16][4096][64]
  short* vt   = (short*)(ws + 27265024);    // 8 MB [16][64][4096]
  short* r    = (short*)(ws + 35653632);    // 8 MB [8192,512]

  pack_all<<<8194, 256, 0, stream>>>(x, Wq, Wk, Wv, Wo, bo, gq, gk, gv, go,
                                     xb, Wcat, Wog, bog);
  gemm_qkv<<<dim3(12, 64), 256, 0, stream>>>(xb, Wcat, qt, kbuf, vt);
  attn<<<dim3(16, 16), 512, 0, stream>>>(qt, kbuf, vt, r);
  gemm_out<<<dim3(4, 64), 256, 0, stream>>>(r, Wog, bog, (float*)d_out);
}

// Round 14
// 196.217 us; speedup vs baseline: 1.0253x; 1.0253x over previous
//
#include <hip/hip_runtime.h>
#include <hip/hip_bf16.h>
#include <math.h>

// B=2, N=4096, D=512, H=8, DH=64, SCALE=1/8 (folded into Wq pack)
// ROUND-14: clean revert to the round-11 configuration (193.2us, session
// best). r13's ring-3 GEMM conversion regressed: at 3 WG/CU the 2-barrier
// loop's drain was already hidden by implicit inter-WG wave overlap (m114),
// and SYNC_TILE's sched_barrier(0) fences pinned the compiler schedule
// (m141-class regression). Counted-vmcnt rings pay only at 1 WG/CU (attn).

typedef __attribute__((ext_vector_type(8))) short short8;
typedef __attribute__((ext_vector_type(4))) float floatx4;
typedef __attribute__((ext_vector_type(16))) float floatx16;
typedef __attribute__((ext_vector_type(4))) short shortx4;
typedef __attribute__((ext_vector_type(4))) int intx4;

__device__ __forceinline__ short f2bf(float f) {
  __hip_bfloat16 h = __float2bfloat16(f);
  return __builtin_bit_cast(short, h);
}

__device__ __forceinline__ float fexp2(float x) {
  float r;
  asm("v_exp_f32 %0, %1" : "=v"(r) : "v"(x));
  return r;
}

__device__ __forceinline__ int cvtpk(float lo, float hi) {
  int r;
  asm("v_cvt_pk_bf16_f32 %0, %1, %2" : "=v"(r) : "v"(lo), "v"(hi));
  return r;
}

__device__ __forceinline__ void gl_lds16(const void* g, void* l) {
  __builtin_amdgcn_global_load_lds(
      (__attribute__((address_space(1))) void*)(g),
      (__attribute__((address_space(3))) void*)(l), 16, 0, 0);
}

// ---------------- combined pack kernel ----------------

__global__ __launch_bounds__(256) void pack_all(
    const float* __restrict__ x,
    const float* __restrict__ Wq, const float* __restrict__ Wk,
    const float* __restrict__ Wv, const float* __restrict__ Wo,
    const float* __restrict__ bo,
    const float* __restrict__ gq, const float* __restrict__ gk,
    const float* __restrict__ gv, const float* __restrict__ go,
    short* __restrict__ xb, short* __restrict__ Wcat,
    short* __restrict__ Wog, float* __restrict__ bog) {
  int b = blockIdx.x;
  int tid = threadIdx.x;
  if (b < 4096) {
    int i = b * 256 + tid;
    floatx4 v = *(const floatx4*)(x + (size_t)i * 4);
    shortx4 o;
    o[0] = f2bf(v[0]); o[1] = f2bf(v[1]); o[2] = f2bf(v[2]); o[3] = f2bf(v[3]);
    *(shortx4*)(xb + (size_t)i * 4) = o;
  } else {
    int i = (b - 4096) * 256 + tid;
    if (i < 786432) {                 // Wcat [1536,512]
      int j = i >> 9, kx = i & 511;
      int seg = j >> 9, jj = j & 511;
      float g, w;
      // fold SCALE=0.125 (exact pow2) ONLY — PROVEN numerics (9-for-9 at
      // the 1.2207e-4 floor). Do NOT fold log2e (2-for-2 failures r6/r9).
      if (seg == 0)      { g = gq[jj] * 0.125f; w = Wq[jj * 512 + kx]; }
      else if (seg == 1) { g = gk[jj];          w = Wk[jj * 512 + kx]; }
      else               { g = gv[jj];          w = Wv[jj * 512 + kx]; }
      Wcat[i] = f2bf(g * w);
    } else if (i < 786432 + 262144) { // Wog [512,512]
      int i2 = i - 786432;
      Wog[i2] = f2bf(go[i2 >> 9] * Wo[i2]);
    } else if (i < 786432 + 262144 + 512) {
      int i3 = i - 786432 - 262144;
      bog[i3] = go[i3] * bo[i3];
    }
  }
}

// ---------------- QKV projection GEMM ----------------

__global__ __launch_bounds__(256) void gemm_qkv(
    const short* __restrict__ A, const short* __restrict__ W,
    short* __restrict__ qt, short* __restrict__ k, short* __restrict__ vt) {
  __shared__ short As[128 * 32];
  __shared__ short Bs[128 * 32];
  const int tid = threadIdx.x;
  const int lane = tid & 63, wv = tid >> 6;
  const int wm = wv & 1, wn = wv >> 1;
  const int lrow = lane & 15, quad = lane >> 4;
  const int lin = blockIdx.y * 12 + blockIdx.x;   // 768 wgs total
  const int wg = (lin & 7) * 96 + (lin >> 3);     // bijective: 768 % 8 == 0
  const int m0 = (wg / 12) * 128, n0 = (wg % 12) * 128;
  const int srow = lane >> 2, skc = lane & 3;

  floatx4 acc[4][4];
  const floatx4 z4 = {0.f, 0.f, 0.f, 0.f};
#pragma unroll
  for (int a = 0; a < 4; a++)
#pragma unroll
    for (int b = 0; b < 4; b++) acc[a][b] = z4;

  for (int kk = 0; kk < 512; kk += 32) {
#pragma unroll
    for (int i = 0; i < 2; i++) {
      int rr = (wv * 2 + i) * 16 + srow;
      gl_lds16(A + (size_t)(m0 + rr) * 512 + kk + skc * 8, As + (wv * 2 + i) * 512);
      gl_lds16(W + (size_t)(n0 + rr) * 512 + kk + skc * 8, Bs + (wv * 2 + i) * 512);
    }
    __syncthreads();
    short8 af[4], bfr[4];
#pragma unroll
    for (int t = 0; t < 4; t++) {
      af[t]  = *(const short8*)(As + (wm * 64 + t * 16 + lrow) * 32 + quad * 8);
      bfr[t] = *(const short8*)(Bs + (wn * 64 + t * 16 + lrow) * 32 + quad * 8);
    }
#pragma unroll
    for (int mt = 0; mt < 4; mt++)
#pragma unroll
      for (int nt = 0; nt < 4; nt++)
        acc[mt][nt] = __builtin_amdgcn_mfma_f32_16x16x32_bf16(af[mt], bfr[nt], acc[mt][nt], 0, 0, 0);
    __syncthreads();
  }

#pragma unroll
  for (int mt = 0; mt < 4; mt++)
#pragma unroll
    for (int nt = 0; nt < 4; nt++) {
      int gj = n0 + wn * 64 + nt * 16 + lrow;
      int seg = gj >> 9, hd = gj & 511;
      int hh = hd >> 6, dd = hd & 63;
      int gi0 = m0 + wm * 64 + mt * 16 + quad * 4;
      int bb = gi0 >> 12, nn = gi0 & 4095;
      if (seg == 1) {
        short* dst = k + ((size_t)(bb * 8 + hh) * 4096 + nn) * 64 + dd;
#pragma unroll
        for (int r = 0; r < 4; r++) dst[(size_t)r * 64] = f2bf(acc[mt][nt][r]);
      } else {
        shortx4 pk;
#pragma unroll
        for (int r = 0; r < 4; r++) pk[r] = f2bf(acc[mt][nt][r]);
        short* base = (seg == 0) ? qt : vt;
        *(shortx4*)(base + ((size_t)(bb * 8 + hh) * 64 + dd) * 4096 + nn) = pk;
      }
    }
}

// ---------------- flash attention (64q/wave, ring-4, counted vmcnt) -------

__global__ __launch_bounds__(512, 2) void attn(
    const short* __restrict__ Qt, const short* __restrict__ K,
    const short* __restrict__ Vt, short* __restrict__ R) {
  __shared__ short SMEM[65536];   // 128KB: K rings [0,32768), V rings [32768,65536)
  const int tid = threadIdx.x;
  const int lane = tid & 63, wv = tid >> 6;      // wv 0..7
  const int l31 = lane & 31, lh = lane >> 5;
  const int pr = wv >> 1, hf = wv & 1;           // pr: q-group 0..3, hf: kv-half
  const int lin = blockIdx.y * 16 + blockIdx.x;  // 256 wgs total
  const int wg = ((lin & 7) << 5) | (lin >> 3);  // bijective: 256 % 8 == 0
  const int bh = wg >> 4;
  const int q0 = (wg & 15) * 256 + pr * 64;

  const short* Qb = Qt + (size_t)bh * 64 * 4096;
  const short* Kb = K + (size_t)bh * 4096 * 64;
  const short* Vb = Vt + (size_t)bh * 64 * 4096;

  short8 qf[2][4];
#pragma unroll
  for (int qt = 0; qt < 2; qt++)
#pragma unroll
    for (int ks = 0; ks < 4; ks++)
#pragma unroll
      for (int i = 0; i < 8; i++)
        qf[qt][ks][i] = Qb[(size_t)(ks * 16 + lh * 8 + i) * 4096 + q0 + qt * 32 + l31];
  asm volatile("s_waitcnt vmcnt(0)" ::: "memory");   // clean slate for counted vmcnt
  __builtin_amdgcn_sched_barrier(0);

  floatx16 O[2][2];
#pragma unroll
  for (int qt = 0; qt < 2; qt++)
#pragma unroll
    for (int dt = 0; dt < 2; dt++)
#pragma unroll
      for (int r = 0; r < 16; r++) O[qt][dt][r] = 0.f;
  float lsum[2] = {0.f, 0.f};

  auto stage = [&](int t, int s) {
    int n0 = (hf * 32 + t) * 64;
    short* Kd = SMEM + (hf * 4 + s) * 4096;
    short* Vd = SMEM + 32768 + (hf * 4 + s) * 4096;
#pragma unroll
    for (int i = 0; i < 2; i++) {
      int ci = i * 4 + pr;
      gl_lds16(Kb + (size_t)(n0 + (ci >> 2) * 32 + l31) * 64 + (ci & 3) * 16 + lh * 8,
               Kd + ci * 512);
      gl_lds16(Vb + (size_t)((ci >> 2) * 32 + l31) * 4096 + n0 + ((ci >> 1) & 1) * 32 + (ci & 1) * 16 + lh * 8,
               Vd + ci * 512);
    }
  };

  auto compute = [&](int s) {
    const short* Kc = SMEM + (hf * 4 + s) * 4096;
    const short* Vc = SMEM + 32768 + (hf * 4 + s) * 4096;
    const float C0 = 1.44269504088896f;           // log2(e)
    const float C1 = -3.0f * 1.44269504088896f;   // fixed shift M=3
#pragma unroll
    for (int mt = 0; mt < 2; mt++) {
      short8 kf[4];
#pragma unroll
      for (int ks = 0; ks < 4; ks++)
        kf[ks] = *(const short8*)(Kc + ((mt * 4 + ks) * 64 + lane) * 8);

      short8 pf[2][2];
#pragma unroll
      for (int qt = 0; qt < 2; qt++) {
        floatx16 S;
#pragma unroll
        for (int r = 0; r < 16; r++) S[r] = 0.f;
#pragma unroll
        for (int ks = 0; ks < 4; ks++)
          S = __builtin_amdgcn_mfma_f32_32x32x16_bf16(kf[ks], qf[qt][ks], S, 0, 0, 0);

        float p[16];
        float l0 = 0.f, l1 = 0.f, l2 = 0.f, l3 = 0.f;
#pragma unroll
        for (int r = 0; r < 16; r += 4) {
          p[r]     = fexp2(fmaf(S[r],     C0, C1)); l0 += p[r];
          p[r + 1] = fexp2(fmaf(S[r + 1], C0, C1)); l1 += p[r + 1];
          p[r + 2] = fexp2(fmaf(S[r + 2], C0, C1)); l2 += p[r + 2];
          p[r + 3] = fexp2(fmaf(S[r + 3], C0, C1)); l3 += p[r + 3];
        }
        lsum[qt] += (l0 + l1) + (l2 + l3);
#pragma unroll
        for (int kh = 0; kh < 2; kh++) {
          int A0 = cvtpk(p[8 * kh + 0], p[8 * kh + 1]);
          int B0 = cvtpk(p[8 * kh + 4], p[8 * kh + 5]);
          int A1 = cvtpk(p[8 * kh + 2], p[8 * kh + 3]);
          int B1 = cvtpk(p[8 * kh + 6], p[8 * kh + 7]);
          asm("v_permlane32_swap_b32 %0, %1" : "+v"(A0), "+v"(B0));
          asm("v_permlane32_swap_b32 %0, %1" : "+v"(A1), "+v"(B1));
          intx4 w4 = {A0, A1, B0, B1};
          pf[qt][kh] = __builtin_bit_cast(short8, w4);
        }
      }

#pragma unroll
      for (int kh = 0; kh < 2; kh++)
#pragma unroll
        for (int dt = 0; dt < 2; dt++) {
          short8 vf = *(const short8*)(Vc + (((dt * 2 + mt) * 2 + kh) * 64 + lane) * 8);
#pragma unroll
          for (int qt = 0; qt < 2; qt++)
            O[qt][dt] = __builtin_amdgcn_mfma_f32_32x32x16_bf16(vf, pf[qt][kh], O[qt][dt], 0, 0, 0);
        }
    }
  };

#define SYNC_TILE(NSTR)                                        \
  asm volatile("s_waitcnt vmcnt(" NSTR ")" ::: "memory");      \
  __builtin_amdgcn_sched_barrier(0);                           \
  asm volatile("s_barrier" ::: "memory");                      \
  __builtin_amdgcn_sched_barrier(0);

  stage(0, 0); stage(1, 1); stage(2, 2);

  for (int t = 0; t < 29; t++) {
    SYNC_TILE("8")
    stage(t + 3, (t + 3) & 3);
    compute(t & 3);
  }
  SYNC_TILE("8")
  compute(1);
  SYNC_TILE("4")
  compute(2);
  SYNC_TILE("0")
  compute(3);
#undef SYNC_TILE

#pragma unroll
  for (int qt = 0; qt < 2; qt++) lsum[qt] += __shfl_xor(lsum[qt], 32, 64);

  __syncthreads();
  float* Ob = (float*)SMEM;
  float* Lb = Ob + 4 * 64 * 65;
  if (hf == 1) {
    int base = (pr * 64 + lane) * 65;
#pragma unroll
    for (int qt = 0; qt < 2; qt++) {
#pragma unroll
      for (int dt = 0; dt < 2; dt++)
#pragma unroll
        for (int r = 0; r < 16; r++)
          Ob[base + qt * 32 + dt * 16 + r] = O[qt][dt][r];
      Lb[(pr * 64 + lane) * 2 + qt] = lsum[qt];
    }
  }
  __syncthreads();
  if (hf == 0) {
    int base = (pr * 64 + lane) * 65;
    const int b = bh >> 3, h = bh & 7;
#pragma unroll
    for (int qt = 0; qt < 2; qt++) {
      float tot = lsum[qt] + Lb[(pr * 64 + lane) * 2 + qt];
      float inv = 1.0f / tot;
      int row = q0 + qt * 32 + l31;
#pragma unroll
      for (int dt = 0; dt < 2; dt++)
#pragma unroll
        for (int g = 0; g < 4; g++) {
          shortx4 pk;
#pragma unroll
          for (int j = 0; j < 4; j++) {
            float v = O[qt][dt][g * 4 + j] + Ob[base + qt * 32 + dt * 16 + g * 4 + j];
            pk[j] = f2bf(v * inv);
          }
          int d0 = dt * 32 + g * 8 + lh * 4;
          *(shortx4*)(&R[((size_t)b * 4096 + row) * 512 + h * 64 + d0]) = pk;
        }
    }
  }
}

// ---------------- output projection GEMM (f32 out + bias) ----------------

__global__ __launch_bounds__(256) void gemm_out(
    const short* __restrict__ A, const short* __restrict__ W,
    const float* __restrict__ bias, float* __restrict__ out) {
  __shared__ short As[128 * 32];
  __shared__ short Bs[128 * 32];
  const int tid = threadIdx.x;
  const int lane = tid & 63, wv = tid >> 6;
  const int wm = wv & 1, wn = wv >> 1;
  const int lrow = lane & 15, quad = lane >> 4;
  const int m0 = blockIdx.y * 128, n0 = blockIdx.x * 128;
  const int srow = lane >> 2, skc = lane & 3;

  floatx4 acc[4][4];
  const floatx4 z4 = {0.f, 0.f, 0.f, 0.f};
#pragma unroll
  for (int a = 0; a < 4; a++)
#pragma unroll
    for (int b = 0; b < 4; b++) acc[a][b] = z4;

  for (int kk = 0; kk < 512; kk += 32) {
#pragma unroll
    for (int i = 0; i < 2; i++) {
      int rr = (wv * 2 + i) * 16 + srow;
      gl_lds16(A + (size_t)(m0 + rr) * 512 + kk + skc * 8, As + (wv * 2 + i) * 512);
      gl_lds16(W + (size_t)(n0 + rr) * 512 + kk + skc * 8, Bs + (wv * 2 + i) * 512);
    }
    __syncthreads();
    short8 af[4], bfr[4];
#pragma unroll
    for (int t = 0; t < 4; t++) {
      af[t]  = *(const short8*)(As + (wm * 64 + t * 16 + lrow) * 32 + quad * 8);
      bfr[t] = *(const short8*)(Bs + (wn * 64 + t * 16 + lrow) * 32 + quad * 8);
    }
#pragma unroll
    for (int mt = 0; mt < 4; mt++)
#pragma unroll
      for (int nt = 0; nt < 4; nt++)
        acc[mt][nt] = __builtin_amdgcn_mfma_f32_16x16x32_bf16(af[mt], bfr[nt], acc[mt][nt], 0, 0, 0);
    __syncthreads();
  }

#pragma unroll
  for (int mt = 0; mt < 4; mt++)
#pragma unroll
    for (int nt = 0; nt < 4; nt++)
#pragma unroll
      for (int r = 0; r < 4; r++) {
        int gi = m0 + wm * 64 + mt * 16 + quad * 4 + r;
        int gj = n0 + wn * 64 + nt * 16 + lrow;
        out[(size_t)gi * 512 + gj] = acc[mt][nt][r] + bias[gj];
      }
}

// ---------------- launcher ----------------

extern "C" void kernel_launch(void* const* d_in, const int* in_sizes, int n_in,
                              void* d_out, int out_size, void* d_ws, size_t ws_size,
                              hipStream_t stream) {
  const float* x  = (const float*)d_in[0];
  const float* Wq = (const float*)d_in[1];
  const float* Wk = (const float*)d_in[2];
  const float* Wv = (const float*)d_in[3];
  const float* Wo = (const float*)d_in[4];
  const float* bo = (const float*)d_in[5];
  const float* gq = (const float*)d_in[6];
  const float* gk = (const float*)d_in[7];
  const float* gv = (const float*)d_in[8];
  const float* go = (const float*)d_in[9];

  char* ws = (char*)d_ws;
  short* xb   = (short*)(ws);               // 8 MB  [8192,512] bf16
  short* Wcat = (short*)(ws + 8388608);     // 1.5 MB [1536,512] bf16
  short* Wog  = (short*)(ws + 9961472);     // 0.5 MB [512,512] bf16
  float* bog  = (float*)(ws + 10485760);    // 2 KB
  short* qt   = (short*)(ws + 10487808);    // 8 MB [16][64][4096]
  short* kbuf = (short*)(ws + 18876416);    // 8 MB [16][4096][64]
  short* vt   = (short*)(ws + 27265024);    // 8 MB [16][64][4096]
  short* r    = (short*)(ws + 35653632);    // 8 MB [8192,512]

  pack_all<<<8194, 256, 0, stream>>>(x, Wq, Wk, Wv, Wo, bo, gq, gk, gv, go,
                                     xb, Wcat, Wog, bog);
  gemm_qkv<<<dim3(12, 64), 256, 0, stream>>>(xb, Wcat, qt, kbuf, vt);
  attn<<<dim3(16, 16), 512, 0, stream>>>(qt, kbuf, vt, r);
  gemm_out<<<dim3(4, 64), 256, 0, stream>>>(r, Wog, bog, (float*)d_out);
}

// Round 15
// 194.454 us; speedup vs baseline: 1.0346x; 1.0091x over previous
//
#include <hip/hip_runtime.h>
#include <hip/hip_bf16.h>
#include <math.h>

// B=2, N=4096, D=512, H=8, DH=64, SCALE=1/8 (folded into Wq pack)
// ROUND-15: r14 confirmed cross-container noise +-4us (same source: 193.2 /
// 196.2) and attn variance 85-96us is silicon, not code. Final theory-backed
// edit: gemm_out was the only MFMA kernel WITHOUT the T1 XCD swizzle — its
// 4 n-panel blocks sharing one A row-panel round-robin onto 4 different
// XCDs, re-fetching the 8MB r matrix up to 4x from HBM. Bijective swizzle
// (256%8==0) gives each XCD 8 contiguous m-panels x all 4 n-panels ->
// per-XCD A slice 1MB, L2-resident across reuse. Everything else is the
// r11/r14-proven configuration.

typedef __attribute__((ext_vector_type(8))) short short8;
typedef __attribute__((ext_vector_type(4))) float floatx4;
typedef __attribute__((ext_vector_type(16))) float floatx16;
typedef __attribute__((ext_vector_type(4))) short shortx4;
typedef __attribute__((ext_vector_type(4))) int intx4;

__device__ __forceinline__ short f2bf(float f) {
  __hip_bfloat16 h = __float2bfloat16(f);
  return __builtin_bit_cast(short, h);
}

__device__ __forceinline__ float fexp2(float x) {
  float r;
  asm("v_exp_f32 %0, %1" : "=v"(r) : "v"(x));
  return r;
}

__device__ __forceinline__ int cvtpk(float lo, float hi) {
  int r;
  asm("v_cvt_pk_bf16_f32 %0, %1, %2" : "=v"(r) : "v"(lo), "v"(hi));
  return r;
}

__device__ __forceinline__ void gl_lds16(const void* g, void* l) {
  __builtin_amdgcn_global_load_lds(
      (__attribute__((address_space(1))) void*)(g),
      (__attribute__((address_space(3))) void*)(l), 16, 0, 0);
}

// ---------------- combined pack kernel ----------------

__global__ __launch_bounds__(256) void pack_all(
    const float* __restrict__ x,
    const float* __restrict__ Wq, const float* __restrict__ Wk,
    const float* __restrict__ Wv, const float* __restrict__ Wo,
    const float* __restrict__ bo,
    const float* __restrict__ gq, const float* __restrict__ gk,
    const float* __restrict__ gv, const float* __restrict__ go,
    short* __restrict__ xb, short* __restrict__ Wcat,
    short* __restrict__ Wog, float* __restrict__ bog) {
  int b = blockIdx.x;
  int tid = threadIdx.x;
  if (b < 4096) {
    int i = b * 256 + tid;
    floatx4 v = *(const floatx4*)(x + (size_t)i * 4);
    shortx4 o;
    o[0] = f2bf(v[0]); o[1] = f2bf(v[1]); o[2] = f2bf(v[2]); o[3] = f2bf(v[3]);
    *(shortx4*)(xb + (size_t)i * 4) = o;
  } else {
    int i = (b - 4096) * 256 + tid;
    if (i < 786432) {                 // Wcat [1536,512]
      int j = i >> 9, kx = i & 511;
      int seg = j >> 9, jj = j & 511;
      float g, w;
      // fold SCALE=0.125 (exact pow2) ONLY — PROVEN numerics (10-for-10 at
      // the 1.2207e-4 floor). Do NOT fold log2e (2-for-2 failures r6/r9).
      if (seg == 0)      { g = gq[jj] * 0.125f; w = Wq[jj * 512 + kx]; }
      else if (seg == 1) { g = gk[jj];          w = Wk[jj * 512 + kx]; }
      else               { g = gv[jj];          w = Wv[jj * 512 + kx]; }
      Wcat[i] = f2bf(g * w);
    } else if (i < 786432 + 262144) { // Wog [512,512]
      int i2 = i - 786432;
      Wog[i2] = f2bf(go[i2 >> 9] * Wo[i2]);
    } else if (i < 786432 + 262144 + 512) {
      int i3 = i - 786432 - 262144;
      bog[i3] = go[i3] * bo[i3];
    }
  }
}

// ---------------- QKV projection GEMM ----------------
// C[8192,1536] = xb @ Wcat^T; k stored [bh][n][64]; q AND v stored transposed
// [bh][64][n] directly from the epilogue. XCD swizzle (T1): 768 wgs, 96
// contiguous per XCD. 2-barrier loop: at 3 WG/CU the drain is hidden by
// implicit inter-WG overlap (r13 proved the pinned ring is WORSE here).

__global__ __launch_bounds__(256) void gemm_qkv(
    const short* __restrict__ A, const short* __restrict__ W,
    short* __restrict__ qt, short* __restrict__ k, short* __restrict__ vt) {
  __shared__ short As[128 * 32];
  __shared__ short Bs[128 * 32];
  const int tid = threadIdx.x;
  const int lane = tid & 63, wv = tid >> 6;
  const int wm = wv & 1, wn = wv >> 1;
  const int lrow = lane & 15, quad = lane >> 4;
  const int lin = blockIdx.y * 12 + blockIdx.x;   // 768 wgs total
  const int wg = (lin & 7) * 96 + (lin >> 3);     // bijective: 768 % 8 == 0
  const int m0 = (wg / 12) * 128, n0 = (wg % 12) * 128;
  const int srow = lane >> 2, skc = lane & 3;

  floatx4 acc[4][4];
  const floatx4 z4 = {0.f, 0.f, 0.f, 0.f};
#pragma unroll
  for (int a = 0; a < 4; a++)
#pragma unroll
    for (int b = 0; b < 4; b++) acc[a][b] = z4;

  for (int kk = 0; kk < 512; kk += 32) {
#pragma unroll
    for (int i = 0; i < 2; i++) {
      int rr = (wv * 2 + i) * 16 + srow;
      gl_lds16(A + (size_t)(m0 + rr) * 512 + kk + skc * 8, As + (wv * 2 + i) * 512);
      gl_lds16(W + (size_t)(n0 + rr) * 512 + kk + skc * 8, Bs + (wv * 2 + i) * 512);
    }
    __syncthreads();
    short8 af[4], bfr[4];
#pragma unroll
    for (int t = 0; t < 4; t++) {
      af[t]  = *(const short8*)(As + (wm * 64 + t * 16 + lrow) * 32 + quad * 8);
      bfr[t] = *(const short8*)(Bs + (wn * 64 + t * 16 + lrow) * 32 + quad * 8);
    }
#pragma unroll
    for (int mt = 0; mt < 4; mt++)
#pragma unroll
      for (int nt = 0; nt < 4; nt++)
        acc[mt][nt] = __builtin_amdgcn_mfma_f32_16x16x32_bf16(af[mt], bfr[nt], acc[mt][nt], 0, 0, 0);
    __syncthreads();
  }

#pragma unroll
  for (int mt = 0; mt < 4; mt++)
#pragma unroll
    for (int nt = 0; nt < 4; nt++) {
      int gj = n0 + wn * 64 + nt * 16 + lrow;
      int seg = gj >> 9, hd = gj & 511;
      int hh = hd >> 6, dd = hd & 63;
      int gi0 = m0 + wm * 64 + mt * 16 + quad * 4;
      int bb = gi0 >> 12, nn = gi0 & 4095;
      if (seg == 1) {
        short* dst = k + ((size_t)(bb * 8 + hh) * 4096 + nn) * 64 + dd;
#pragma unroll
        for (int r = 0; r < 4; r++) dst[(size_t)r * 64] = f2bf(acc[mt][nt][r]);
      } else {
        shortx4 pk;
#pragma unroll
        for (int r = 0; r < 4; r++) pk[r] = f2bf(acc[mt][nt][r]);
        short* base = (seg == 0) ? qt : vt;
        *(shortx4*)(base + ((size_t)(bb * 8 + hh) * 64 + dd) * 4096 + nn) = pk;
      }
    }
}

// ---------------- flash attention (64q/wave, ring-4, counted vmcnt) -------
// Verified r11/r12/r14: 85-96us (container variance), absmax = exact
// 1.2207e-4 floor. Numerics: scale-only pack, S zero-init,
// p = exp2(fma(S, log2e, -3*log2e)); p <= ~0.2 bf16-P profile.
// Structure: ring-4 staging (128KB LDS, 1 WG/CU, prefetch distance 3,
// vmcnt(8)); hardened sync (counted s_waitcnt + sched_barrier + s_barrier +
// sched_barrier — needed at 1 WG/CU where no co-resident waves hide the
// drain). WG = 512 thr = 4 pr (64q) x 2 hf (2048 kv); 256 WGs, XCD-swizzled
// (2 heads/XCD, K/V L2-resident). Halves combined in-LDS (stride-65 f32).
// Structural plateau: >2 waves/SIMD needs staging beyond 160KB/CU or >256
// VGPR at every feasible tiling.

__global__ __launch_bounds__(512, 2) void attn(
    const short* __restrict__ Qt, const short* __restrict__ K,
    const short* __restrict__ Vt, short* __restrict__ R) {
  __shared__ short SMEM[65536];   // 128KB: K rings [0,32768), V rings [32768,65536)
  const int tid = threadIdx.x;
  const int lane = tid & 63, wv = tid >> 6;      // wv 0..7
  const int l31 = lane & 31, lh = lane >> 5;
  const int pr = wv >> 1, hf = wv & 1;           // pr: q-group 0..3, hf: kv-half
  const int lin = blockIdx.y * 16 + blockIdx.x;  // 256 wgs total
  const int wg = ((lin & 7) << 5) | (lin >> 3);  // bijective: 256 % 8 == 0
  const int bh = wg >> 4;
  const int q0 = (wg & 15) * 256 + pr * 64;

  const short* Qb = Qt + (size_t)bh * 64 * 4096;
  const short* Kb = K + (size_t)bh * 4096 * 64;
  const short* Vb = Vt + (size_t)bh * 64 * 4096;

  short8 qf[2][4];
#pragma unroll
  for (int qt = 0; qt < 2; qt++)
#pragma unroll
    for (int ks = 0; ks < 4; ks++)
#pragma unroll
      for (int i = 0; i < 8; i++)
        qf[qt][ks][i] = Qb[(size_t)(ks * 16 + lh * 8 + i) * 4096 + q0 + qt * 32 + l31];
  asm volatile("s_waitcnt vmcnt(0)" ::: "memory");   // clean slate for counted vmcnt
  __builtin_amdgcn_sched_barrier(0);

  floatx16 O[2][2];
#pragma unroll
  for (int qt = 0; qt < 2; qt++)
#pragma unroll
    for (int dt = 0; dt < 2; dt++)
#pragma unroll
      for (int r = 0; r < 16; r++) O[qt][dt][r] = 0.f;
  float lsum[2] = {0.f, 0.f};

  auto stage = [&](int t, int s) {
    int n0 = (hf * 32 + t) * 64;
    short* Kd = SMEM + (hf * 4 + s) * 4096;
    short* Vd = SMEM + 32768 + (hf * 4 + s) * 4096;
#pragma unroll
    for (int i = 0; i < 2; i++) {
      int ci = i * 4 + pr;
      gl_lds16(Kb + (size_t)(n0 + (ci >> 2) * 32 + l31) * 64 + (ci & 3) * 16 + lh * 8,
               Kd + ci * 512);
      gl_lds16(Vb + (size_t)((ci >> 2) * 32 + l31) * 4096 + n0 + ((ci >> 1) & 1) * 32 + (ci & 1) * 16 + lh * 8,
               Vd + ci * 512);
    }
  };

  auto compute = [&](int s) {
    const short* Kc = SMEM + (hf * 4 + s) * 4096;
    const short* Vc = SMEM + 32768 + (hf * 4 + s) * 4096;
    const float C0 = 1.44269504088896f;           // log2(e)
    const float C1 = -3.0f * 1.44269504088896f;   // fixed shift M=3
#pragma unroll
    for (int mt = 0; mt < 2; mt++) {
      short8 kf[4];
#pragma unroll
      for (int ks = 0; ks < 4; ks++)
        kf[ks] = *(const short8*)(Kc + ((mt * 4 + ks) * 64 + lane) * 8);

      short8 pf[2][2];
#pragma unroll
      for (int qt = 0; qt < 2; qt++) {
        floatx16 S;
#pragma unroll
        for (int r = 0; r < 16; r++) S[r] = 0.f;
#pragma unroll
        for (int ks = 0; ks < 4; ks++)
          S = __builtin_amdgcn_mfma_f32_32x32x16_bf16(kf[ks], qf[qt][ks], S, 0, 0, 0);

        float p[16];
        float l0 = 0.f, l1 = 0.f, l2 = 0.f, l3 = 0.f;
#pragma unroll
        for (int r = 0; r < 16; r += 4) {
          p[r]     = fexp2(fmaf(S[r],     C0, C1)); l0 += p[r];
          p[r + 1] = fexp2(fmaf(S[r + 1], C0, C1)); l1 += p[r + 1];
          p[r + 2] = fexp2(fmaf(S[r + 2], C0, C1)); l2 += p[r + 2];
          p[r + 3] = fexp2(fmaf(S[r + 3], C0, C1)); l3 += p[r + 3];
        }
        lsum[qt] += (l0 + l1) + (l2 + l3);
#pragma unroll
        for (int kh = 0; kh < 2; kh++) {
          int A0 = cvtpk(p[8 * kh + 0], p[8 * kh + 1]);
          int B0 = cvtpk(p[8 * kh + 4], p[8 * kh + 5]);
          int A1 = cvtpk(p[8 * kh + 2], p[8 * kh + 3]);
          int B1 = cvtpk(p[8 * kh + 6], p[8 * kh + 7]);
          asm("v_permlane32_swap_b32 %0, %1" : "+v"(A0), "+v"(B0));
          asm("v_permlane32_swap_b32 %0, %1" : "+v"(A1), "+v"(B1));
          intx4 w4 = {A0, A1, B0, B1};
          pf[qt][kh] = __builtin_bit_cast(short8, w4);
        }
      }

#pragma unroll
      for (int kh = 0; kh < 2; kh++)
#pragma unroll
        for (int dt = 0; dt < 2; dt++) {
          short8 vf = *(const short8*)(Vc + (((dt * 2 + mt) * 2 + kh) * 64 + lane) * 8);
#pragma unroll
          for (int qt = 0; qt < 2; qt++)
            O[qt][dt] = __builtin_amdgcn_mfma_f32_32x32x16_bf16(vf, pf[qt][kh], O[qt][dt], 0, 0, 0);
        }
    }
  };

#define SYNC_TILE(NSTR)                                        \
  asm volatile("s_waitcnt vmcnt(" NSTR ")" ::: "memory");      \
  __builtin_amdgcn_sched_barrier(0);                           \
  asm volatile("s_barrier" ::: "memory");                      \
  __builtin_amdgcn_sched_barrier(0);

  stage(0, 0); stage(1, 1); stage(2, 2);

  for (int t = 0; t < 29; t++) {
    SYNC_TILE("8")
    stage(t + 3, (t + 3) & 3);
    compute(t & 3);
  }
  SYNC_TILE("8")
  compute(1);
  SYNC_TILE("4")
  compute(2);
  SYNC_TILE("0")
  compute(3);
#undef SYNC_TILE

#pragma unroll
  for (int qt = 0; qt < 2; qt++) lsum[qt] += __shfl_xor(lsum[qt], 32, 64);

  __syncthreads();
  float* Ob = (float*)SMEM;
  float* Lb = Ob + 4 * 64 * 65;
  if (hf == 1) {
    int base = (pr * 64 + lane) * 65;
#pragma unroll
    for (int qt = 0; qt < 2; qt++) {
#pragma unroll
      for (int dt = 0; dt < 2; dt++)
#pragma unroll
        for (int r = 0; r < 16; r++)
          Ob[base + qt * 32 + dt * 16 + r] = O[qt][dt][r];
      Lb[(pr * 64 + lane) * 2 + qt] = lsum[qt];
    }
  }
  __syncthreads();
  if (hf == 0) {
    int base = (pr * 64 + lane) * 65;
    const int b = bh >> 3, h = bh & 7;
#pragma unroll
    for (int qt = 0; qt < 2; qt++) {
      float tot = lsum[qt] + Lb[(pr * 64 + lane) * 2 + qt];
      float inv = 1.0f / tot;
      int row = q0 + qt * 32 + l31;
#pragma unroll
      for (int dt = 0; dt < 2; dt++)
#pragma unroll
        for (int g = 0; g < 4; g++) {
          shortx4 pk;
#pragma unroll
          for (int j = 0; j < 4; j++) {
            float v = O[qt][dt][g * 4 + j] + Ob[base + qt * 32 + dt * 16 + g * 4 + j];
            pk[j] = f2bf(v * inv);
          }
          int d0 = dt * 32 + g * 8 + lh * 4;
          *(shortx4*)(&R[((size_t)b * 4096 + row) * 512 + h * 64 + d0]) = pk;
        }
    }
  }
}

// ---------------- output projection GEMM (f32 out + bias) ----------------
// ROUND-15: + T1 XCD swizzle (the only MFMA kernel that lacked it). 256 wgs,
// 32 contiguous per XCD = 8 m-panels x all 4 n-panels -> per-XCD A slice
// 1MB, L2-resident across the 4x reuse (was: 4 sharing blocks on 4 XCDs,
// up to 4x HBM re-fetch of the 8MB r matrix).

__global__ __launch_bounds__(256) void gemm_out(
    const short* __restrict__ A, const short* __restrict__ W,
    const float* __restrict__ bias, float* __restrict__ out) {
  __shared__ short As[128 * 32];
  __shared__ short Bs[128 * 32];
  const int tid = threadIdx.x;
  const int lane = tid & 63, wv = tid >> 6;
  const int wm = wv & 1, wn = wv >> 1;
  const int lrow = lane & 15, quad = lane >> 4;
  const int lin = blockIdx.y * 4 + blockIdx.x;    // 256 wgs total
  const int wg = ((lin & 7) << 5) | (lin >> 3);   // bijective: 256 % 8 == 0
  const int m0 = (wg >> 2) * 128, n0 = (wg & 3) * 128;
  const int srow = lane >> 2, skc = lane & 3;

  floatx4 acc[4][4];
  const floatx4 z4 = {0.f, 0.f, 0.f, 0.f};
#pragma unroll
  for (int a = 0; a < 4; a++)
#pragma unroll
    for (int b = 0; b < 4; b++) acc[a][b] = z4;

  for (int kk = 0; kk < 512; kk += 32) {
#pragma unroll
    for (int i = 0; i < 2; i++) {
      int rr = (wv * 2 + i) * 16 + srow;
      gl_lds16(A + (size_t)(m0 + rr) * 512 + kk + skc * 8, As + (wv * 2 + i) * 512);
      gl_lds16(W + (size_t)(n0 + rr) * 512 + kk + skc * 8, Bs + (wv * 2 + i) * 512);
    }
    __syncthreads();
    short8 af[4], bfr[4];
#pragma unroll
    for (int t = 0; t < 4; t++) {
      af[t]  = *(const short8*)(As + (wm * 64 + t * 16 + lrow) * 32 + quad * 8);
      bfr[t] = *(const short8*)(Bs + (wn * 64 + t * 16 + lrow) * 32 + quad * 8);
    }
#pragma unroll
    for (int mt = 0; mt < 4; mt++)
#pragma unroll
      for (int nt = 0; nt < 4; nt++)
        acc[mt][nt] = __builtin_amdgcn_mfma_f32_16x16x32_bf16(af[mt], bfr[nt], acc[mt][nt], 0, 0, 0);
    __syncthreads();
  }

#pragma unroll
  for (int mt = 0; mt < 4; mt++)
#pragma unroll
    for (int nt = 0; nt < 4; nt++)
#pragma unroll
      for (int r = 0; r < 4; r++) {
        int gi = m0 + wm * 64 + mt * 16 + quad * 4 + r;
        int gj = n0 + wn * 64 + nt * 16 + lrow;
        out[(size_t)gi * 512 + gj] = acc[mt][nt][r] + bias[gj];
      }
}

// ---------------- launcher ----------------

extern "C" void kernel_launch(void* const* d_in, const int* in_sizes, int n_in,
                              void* d_out, int out_size, void* d_ws, size_t ws_size,
                              hipStream_t stream) {
  const float* x  = (const float*)d_in[0];
  const float* Wq = (const float*)d_in[1];
  const float* Wk = (const float*)d_in[2];
  const float* Wv = (const float*)d_in[3];
  const float* Wo = (const float*)d_in[4];
  const float* bo = (const float*)d_in[5];
  const float* gq = (const float*)d_in[6];
  const float* gk = (const float*)d_in[7];
  const float* gv = (const float*)d_in[8];
  const float* go = (const float*)d_in[9];

  char* ws = (char*)d_ws;
  short* xb   = (short*)(ws);               // 8 MB  [8192,512] bf16
  short* Wcat = (short*)(ws + 8388608);     // 1.5 MB [1536,512] bf16
  short* Wog  = (short*)(ws + 9961472);     // 0.5 MB [512,512] bf16
  float* bog  = (float*)(ws + 10485760);    // 2 KB
  short* qt   = (short*)(ws + 10487808);    // 8 MB [16][64][4096]
  short* kbuf = (short*)(ws + 18876416);    // 8 MB [16][4096][64]
  short* vt   = (short*)(ws + 27265024);    // 8 MB [16][64][4096]
  short* r    = (short*)(ws + 35653632);    // 8 MB [8192,512]

  pack_all<<<8194, 256, 0, stream>>>(x, Wq, Wk, Wv, Wo, bo, gq, gk, gv, go,
                                     xb, Wcat, Wog, bog);
  gemm_qkv<<<dim3(12, 64), 256, 0, stream>>>(xb, Wcat, qt, kbuf, vt);
  attn<<<dim3(16, 16), 512, 0, stream>>>(qt, kbuf, vt, r);
  gemm_out<<<dim3(4, 64), 256, 0, stream>>>(r, Wog, bog, (float*)d_out);
}